// Round 4
// baseline (156.192 us; speedup 1.0000x reference)
//
#include <hip/hip_runtime.h>
#include <math.h>

#define BB 8
#define NN 512
#define DD 512
#define DKK 64
#define NC 192   // 3*DK columns of W_qkv

// (1/sqrt(64)) * log2(e) : fold softmax scale into exp2 domain
#define T_FACT 0.18033688011112042591999058f

#if defined(__has_builtin)
#if __has_builtin(__builtin_amdgcn_exp2f)
#define EXP2F(x) __builtin_amdgcn_exp2f(x)
#else
#define EXP2F(x) exp2f(x)
#endif
#else
#define EXP2F(x) exp2f(x)
#endif

// -------------------------------------------------------------------------
// Kernel 1: FUSED QKV-projection + rank-1 per-channel softmax attention.
// Grid = 512 blocks (one per (b,c) channel), 512 threads (thread t owns
// row n = t).
//   phase A: stage W_qkv columns {c, 64+c, 128+c} into LDS (once, tiny).
//   phase B: q_t,k_t,v_t = X[b,t,:] . w{q,k,v}  — X row read as full 64 B
//            lines into registers (no L1-retention dependence); W read as
//            uniform-address LDS broadcasts (conflict-free).
//   phase C: k,v to LDS; block-reduce kmax/kmin; per-thread softmax over m
//            with the rank-1 stable max  M = t>0 ? t*kmax : t*kmin.
// Occupancy: 4096 waves = 4 waves/SIMD; ~10.3 KB LDS, low VGPR.
// -------------------------------------------------------------------------
__global__ __launch_bounds__(512) void qkv_attn(const float* __restrict__ X,
                                                const float* __restrict__ W,
                                                float* __restrict__ sa_t) {
    __shared__ float wql[DD], wkl[DD], wvl[DD];
    __shared__ float kl[NN], vl[NN];
    __shared__ float red[16];

    const int t = threadIdx.x;
    const int c = blockIdx.x & 63;
    const int b = blockIdx.x >> 6;

    // phase A: stage weight columns (scattered dwords, once per block)
    wql[t] = W[(size_t)t * NC + c];
    wkl[t] = W[(size_t)t * NC + 64 + c];
    wvl[t] = W[(size_t)t * NC + 128 + c];
    __syncthreads();

    // phase B: three dot-products over the thread's own X row
    const float* xrow = X + ((size_t)(b * NN + t)) * DD;
    float qa = 0.f, ka = 0.f, va = 0.f;
    #pragma unroll 4
    for (int d0 = 0; d0 < DD; d0 += 16) {
        float4 x[4];
        #pragma unroll
        for (int i = 0; i < 4; ++i)
            x[i] = *(const float4*)(xrow + d0 + 4 * i);
        #pragma unroll
        for (int i = 0; i < 4; ++i) {
            const float4 wq = *(const float4*)&wql[d0 + 4 * i];
            const float4 wk = *(const float4*)&wkl[d0 + 4 * i];
            const float4 wv = *(const float4*)&wvl[d0 + 4 * i];
            qa = fmaf(x[i].x, wq.x, qa); qa = fmaf(x[i].y, wq.y, qa);
            qa = fmaf(x[i].z, wq.z, qa); qa = fmaf(x[i].w, wq.w, qa);
            ka = fmaf(x[i].x, wk.x, ka); ka = fmaf(x[i].y, wk.y, ka);
            ka = fmaf(x[i].z, wk.z, ka); ka = fmaf(x[i].w, wk.w, ka);
            va = fmaf(x[i].x, wv.x, va); va = fmaf(x[i].y, wv.y, va);
            va = fmaf(x[i].z, wv.z, va); va = fmaf(x[i].w, wv.w, va);
        }
    }

    // phase C: share k,v; block-reduce kmax/kmin (8 waves -> red[])
    kl[t] = ka;
    vl[t] = va;
    float mx = ka, mn = ka;
    #pragma unroll
    for (int off = 32; off > 0; off >>= 1) {
        mx = fmaxf(mx, __shfl_down(mx, off, 64));
        mn = fminf(mn, __shfl_down(mn, off, 64));
    }
    if ((t & 63) == 0) {
        red[t >> 6]     = mx;
        red[8 + (t >> 6)] = mn;
    }
    __syncthreads();
    float kmax = red[0], kmin = red[8];
    #pragma unroll
    for (int i = 1; i < 8; ++i) {
        kmax = fmaxf(kmax, red[i]);
        kmin = fminf(kmin, red[8 + i]);
    }

    const float tt = qa * T_FACT;
    const float M  = tt > 0.f ? tt * kmax : tt * kmin;

    float sw = 0.f, sv = 0.f;
    const float4* k4 = (const float4*)kl;
    const float4* v4 = (const float4*)vl;
    #pragma unroll 4
    for (int j = 0; j < NN / 4; ++j) {
        const float4 kk = k4[j];
        const float4 vv = v4[j];
        const float ke[4] = {kk.x, kk.y, kk.z, kk.w};
        const float ve[4] = {vv.x, vv.y, vv.z, vv.w};
        #pragma unroll
        for (int e = 0; e < 4; ++e) {
            const float w = EXP2F(fmaf(tt, ke[e], -M));
            sw += w;
            sv = fmaf(w, ve[e], sv);
        }
    }
    sa_t[(size_t)blockIdx.x * NN + t] = sv / sw;
}

// -------------------------------------------------------------------------
// Kernel 2: out = SA(4096x64) @ Wo(64x512). sa_t is [b][c][n] (K-major
// per b). 512 threads/block (8 waves), 64x64 tile, 2x4 micro-tile.
// -------------------------------------------------------------------------
__global__ __launch_bounds__(512) void out_gemm(const float* __restrict__ sa_t,
                                                const float* __restrict__ Wo,
                                                float* __restrict__ out) {
    __shared__ float As[64][68];  // As[c][n_local]
    __shared__ float Bs[64][68];  // Bs[c][d_local]

    const int tid  = threadIdx.x;
    const int row0 = blockIdx.x * 64;
    const int d0   = blockIdx.y * 64;
    const int b    = row0 >> 9;
    const int n0   = row0 & 511;

    #pragma unroll
    for (int ss = 0; ss < 2; ++ss) {
        const int s = tid + ss * 512;
        const int cidx = s >> 4;
        const int f    = s & 15;
        *(float4*)&As[cidx][4 * f] =
            *(const float4*)(sa_t + (size_t)(b * DKK + cidx) * NN + n0 + 4 * f);
        *(float4*)&Bs[cidx][4 * f] =
            *(const float4*)(Wo + (size_t)cidx * DD + d0 + 4 * f);
    }
    __syncthreads();

    const int tc = tid & 15;   // 4 cols
    const int tr = tid >> 4;   // 0..31 -> 2 rows
    float acc[2][4] = {};
    #pragma unroll 8
    for (int k = 0; k < DKK; ++k) {
        const float2 a = *(const float2*)&As[k][2 * tr];
        const float4 bv = *(const float4*)&Bs[k][4 * tc];
        const float av[2] = {a.x, a.y};
        const float be[4] = {bv.x, bv.y, bv.z, bv.w};
        #pragma unroll
        for (int i = 0; i < 2; ++i)
            #pragma unroll
            for (int j = 0; j < 4; ++j)
                acc[i][j] = fmaf(av[i], be[j], acc[i][j]);
    }

    float* op = out + ((size_t)(b * NN + n0)) * DD + d0;
    #pragma unroll
    for (int i = 0; i < 2; ++i) {
        const float4 v = {acc[i][0], acc[i][1], acc[i][2], acc[i][3]};
        *(float4*)(op + (size_t)(2 * tr + i) * DD + 4 * tc) = v;
    }
}

extern "C" void kernel_launch(void* const* d_in, const int* in_sizes, int n_in,
                              void* d_out, int out_size, void* d_ws, size_t ws_size,
                              hipStream_t stream) {
    const float* X    = (const float*)d_in[0];  // (8,512,512)
    const float* Wqkv = (const float*)d_in[1];  // (512,192)
    const float* Wo   = (const float*)d_in[2];  // (64,512)
    float* out = (float*)d_out;                 // (8,512,512)

    float* sa_t = (float*)d_ws;                 // [b][c][n], 1 MB

    qkv_attn<<<dim3(BB * DKK), 512, 0, stream>>>(X, Wqkv, sa_t);
    out_gemm<<<dim3(64, 8), 512, 0, stream>>>(sa_t, Wo, out);
}